// Round 1
// baseline (398.146 us; speedup 1.0000x reference)
//
#include <hip/hip_runtime.h>
#include <stdint.h>

#define DIN 128
#define DHID 128
#define DOUT2 64

// ---------------- dtype detector (int32 vs int64 edge_index) ----------------
__global__ void detect_i64_kernel(const unsigned* ei, int* flag) {
    int t = threadIdx.x;
    unsigned hi = ei[2 * t + 1];
    unsigned long long vote = __ballot(hi == 0u);
    if (t == 0) *flag = (vote == ~0ull) ? 1 : 0;
}

// ---------------- degree count (dst side, excluding self loops) ----------------
__global__ void deg_count_kernel(const int* ei32, const long long* ei64, const int* flag,
                                 unsigned* deg, int E) {
    int e = blockIdx.x * blockDim.x + threadIdx.x;
    if (e >= E) return;
    int mode = *flag;
    int d = mode ? (int)ei64[(size_t)E + e] : ei32[(size_t)E + e];
    atomicAdd(&deg[d], 1u);
}

// ---------------- dinv = 1/sqrt(deg+1)  (self loop adds 1) ----------------
__global__ void dinv_kernel(const unsigned* deg, float* dinv, int N) {
    int i = blockIdx.x * blockDim.x + threadIdx.x;
    if (i < N) dinv[i] = 1.0f / sqrtf((float)(deg[i] + 1u));
}

// ---------------- single-block exclusive scan over deg -> row_ptr, cursor ----------------
__global__ __launch_bounds__(1024) void scan_kernel(const unsigned* deg, int* row_ptr,
                                                    int* cursor, int N) {
    __shared__ int s[1024];
    int t = threadIdx.x;
    int C = (N + 1023) / 1024;
    int base = t * C;
    int sum = 0;
    for (int j = 0; j < C; j++) {
        int idx = base + j;
        if (idx < N) sum += (int)deg[idx];
    }
    s[t] = sum;
    __syncthreads();
    for (int off = 1; off < 1024; off <<= 1) {
        int v = (t >= off) ? s[t - off] : 0;
        __syncthreads();
        s[t] += v;
        __syncthreads();
    }
    int running = s[t] - sum;  // exclusive
    for (int j = 0; j < C; j++) {
        int idx = base + j;
        if (idx < N) {
            row_ptr[idx] = running;
            cursor[idx]  = running;
            running += (int)deg[idx];
        }
    }
    if (t == 1023) row_ptr[N] = s[1023];
}

// ---------------- scatter edges into CSR (by dst); store src and w=dinv[src] ----------------
__global__ void scatter_kernel(const int* ei32, const long long* ei64, const int* flag,
                               const float* dinv, int* cursor, int* csr_src, float* csr_w,
                               int E) {
    int e = blockIdx.x * blockDim.x + threadIdx.x;
    if (e >= E) return;
    int mode = *flag;
    int s, d;
    if (mode) {
        s = (int)ei64[e];
        d = (int)ei64[(size_t)E + e];
    } else {
        s = ei32[e];
        d = ei32[(size_t)E + e];
    }
    int pos = atomicAdd(&cursor[d], 1);
    csr_src[pos] = s;
    csr_w[pos] = dinv[s];
}

// ---------------- fp32 GEMM: out[M x DO] = A[M x 128] @ W[128 x DO] ----------------
// BM=64, BK=64, 256 threads. Thread computes RM rows x 4 cols.
template <int DO>
__global__ __launch_bounds__(256, 2) void gemm_kernel(const float* __restrict__ A,
                                                      const float* __restrict__ W,
                                                      float* __restrict__ out, int M) {
    constexpr int CG  = DO / 4;    // col groups of 4
    constexpr int TYN = 256 / CG;  // row groups
    constexpr int RM  = 64 / TYN;  // rows per thread
    __shared__ float As[64 * 64];
    __shared__ float Bs[64 * DO];
    const int tid = threadIdx.x;
    const int row0 = blockIdx.x * 64;
    const int tx = tid % CG, ty = tid / CG;

    float acc[RM][4];
#pragma unroll
    for (int r = 0; r < RM; r++) acc[r][0] = acc[r][1] = acc[r][2] = acc[r][3] = 0.f;

    for (int k0 = 0; k0 < 128; k0 += 64) {
        // stage A chunk (64 rows x 64 cols) as float4
        for (int idx = tid; idx < 64 * 16; idx += 256) {
            int r = idx >> 4, cc = idx & 15;
            int row = row0 + r;
            float4 v = make_float4(0.f, 0.f, 0.f, 0.f);
            if (row < M) v = ((const float4*)A)[(size_t)row * 32 + (k0 >> 2) + cc];
            ((float4*)As)[idx] = v;
        }
        // stage B chunk (rows k0..k0+63 of W)
        for (int idx = tid; idx < 64 * CG; idx += 256) {
            int r = idx / CG, cc = idx % CG;
            ((float4*)Bs)[idx] = ((const float4*)W)[(size_t)(k0 + r) * CG + cc];
        }
        __syncthreads();
#pragma unroll 8
        for (int k = 0; k < 64; k++) {
            float4 b = ((const float4*)Bs)[k * CG + tx];
#pragma unroll
            for (int r = 0; r < RM; r++) {
                float a = As[(ty * RM + r) * 64 + k];
                acc[r][0] = fmaf(a, b.x, acc[r][0]);
                acc[r][1] = fmaf(a, b.y, acc[r][1]);
                acc[r][2] = fmaf(a, b.z, acc[r][2]);
                acc[r][3] = fmaf(a, b.w, acc[r][3]);
            }
        }
        __syncthreads();
    }
#pragma unroll
    for (int r = 0; r < RM; r++) {
        int row = row0 + ty * RM + r;
        if (row < M) {
            float4 v = make_float4(acc[r][0], acc[r][1], acc[r][2], acc[r][3]);
            ((float4*)out)[(size_t)row * CG + tx] = v;
        }
    }
}

// ---------------- CSR aggregation: out[i] = dinv[i]*(dinv[i]*h[i] + sum_e w_e*h[src_e]) + b
template <int D, bool RELU>
__global__ __launch_bounds__(128) void agg_kernel(const float* __restrict__ h,
                                                  const int* __restrict__ csr_src,
                                                  const float* __restrict__ csr_w,
                                                  const int* __restrict__ row_ptr,
                                                  const float* __restrict__ dinv,
                                                  const float* __restrict__ bias,
                                                  float* __restrict__ out, int N) {
    constexpr int CHUNK = 128;
    __shared__ int s_src[CHUNK];
    __shared__ float s_w[CHUNK];
    const int i = blockIdx.x;
    const int c = threadIdx.x;
    const float di = dinv[i];
    float acc = di * h[(size_t)i * D + c];  // self loop (outer di applied at end)
    const int start = row_ptr[i], end = row_ptr[i + 1];
    for (int base = start; base < end; base += CHUNK) {
        int m = min(CHUNK, end - base);
        for (int j = c; j < m; j += D) {
            s_src[j] = csr_src[base + j];
            s_w[j] = csr_w[base + j];
        }
        __syncthreads();
        for (int j = 0; j < m; j++) {
            acc = fmaf(s_w[j], h[(size_t)s_src[j] * D + c], acc);
        }
        __syncthreads();
    }
    float r = di * acc + bias[c];
    out[(size_t)i * D + c] = RELU ? fmaxf(r, 0.f) : r;
}

extern "C" void kernel_launch(void* const* d_in, const int* in_sizes, int n_in,
                              void* d_out, int out_size, void* d_ws, size_t ws_size,
                              hipStream_t stream) {
    const float* x  = (const float*)d_in[0];
    const void*  ei = d_in[1];
    const float* W1 = (const float*)d_in[2];
    const float* b1 = (const float*)d_in[3];
    const float* W2 = (const float*)d_in[4];
    const float* b2 = (const float*)d_in[5];
    float* out = (float*)d_out;

    const int N = in_sizes[0] / DIN;
    const int E = in_sizes[1] / 2;

    char* ws = (char*)d_ws;
    size_t off = 0;
    auto alloc = [&](size_t bytes) -> void* {
        void* p = ws + off;
        off += (bytes + 255) & ~(size_t)255;
        return p;
    };
    unsigned* deg   = (unsigned*)alloc((size_t)N * 4);
    float*    dinv  = (float*)alloc((size_t)N * 4);
    int*      rowp  = (int*)alloc((size_t)(N + 1) * 4);
    int*      curs  = (int*)alloc((size_t)N * 4);
    int*      flag  = (int*)alloc(256);
    int*      csrs  = (int*)alloc((size_t)E * 4);
    float*    csrw  = (float*)alloc((size_t)E * 4);
    float*    h1    = (float*)alloc((size_t)N * DHID * 4);
    float*    o1    = (float*)alloc((size_t)N * DHID * 4);
    float*    h2    = h1;  // h1 dead after agg1; reuse

    hipMemsetAsync(deg, 0, (size_t)N * 4, stream);
    detect_i64_kernel<<<1, 64, 0, stream>>>((const unsigned*)ei, flag);
    deg_count_kernel<<<(E + 255) / 256, 256, 0, stream>>>((const int*)ei, (const long long*)ei,
                                                          flag, deg, E);
    dinv_kernel<<<(N + 255) / 256, 256, 0, stream>>>(deg, dinv, N);
    scan_kernel<<<1, 1024, 0, stream>>>(deg, rowp, curs, N);
    scatter_kernel<<<(E + 255) / 256, 256, 0, stream>>>((const int*)ei, (const long long*)ei,
                                                        flag, dinv, curs, csrs, csrw, E);
    gemm_kernel<DHID><<<(N + 63) / 64, 256, 0, stream>>>(x, W1, h1, N);
    agg_kernel<DHID, true><<<N, DHID, 0, stream>>>(h1, csrs, csrw, rowp, dinv, b1, o1, N);
    gemm_kernel<DOUT2><<<(N + 63) / 64, 256, 0, stream>>>(o1, W2, h2, N);
    agg_kernel<DOUT2, false><<<N, DOUT2, 0, stream>>>(h2, csrs, csrw, rowp, dinv, b2, out, N);
}

// Round 2
// 284.362 us; speedup vs baseline: 1.4001x; 1.4001x over previous
//
#include <hip/hip_runtime.h>
#include <stdint.h>

#define DIN 128
#define DHID 128
#define DOUT2 64

// ---------------- dtype detector (int32 vs int64 edge_index) ----------------
__global__ void detect_i64_kernel(const unsigned* ei, int* flag) {
    int t = threadIdx.x;
    unsigned hi = ei[2 * t + 1];
    unsigned long long vote = __ballot(hi == 0u);
    if (t == 0) *flag = (vote == ~0ull) ? 1 : 0;
}

// ---------------- degree count (dst side, excluding self loops) ----------------
__global__ void deg_count_kernel(const int* ei32, const long long* ei64, const int* flag,
                                 unsigned* deg, int E) {
    int e = blockIdx.x * blockDim.x + threadIdx.x;
    if (e >= E) return;
    int mode = *flag;
    int d = mode ? (int)ei64[(size_t)E + e] : ei32[(size_t)E + e];
    atomicAdd(&deg[d], 1u);
}

// ---------------- dinv = 1/sqrt(deg+1)  (self loop adds 1) ----------------
__global__ void dinv_kernel(const unsigned* deg, float* dinv, int N) {
    int i = blockIdx.x * blockDim.x + threadIdx.x;
    if (i < N) dinv[i] = 1.0f / sqrtf((float)(deg[i] + 1u));
}

// ---------------- hierarchical exclusive scan: deg -> row_ptr, cursor ----------------
// pass 1: per-block (1024 elements) sums
__global__ __launch_bounds__(256) void scan_blocksum_kernel(const unsigned* deg, int* bsum,
                                                            int N) {
    __shared__ int s[256];
    int t = threadIdx.x;
    int base = blockIdx.x * 1024 + t * 4;
    int sum = 0;
    if (base + 3 < N) {
        int4 v = *(const int4*)((const int*)deg + base);
        sum = v.x + v.y + v.z + v.w;
    } else {
        for (int j = 0; j < 4; j++)
            if (base + j < N) sum += (int)deg[base + j];
    }
    s[t] = sum;
    __syncthreads();
    for (int off = 128; off > 0; off >>= 1) {
        if (t < off) s[t] += s[t + off];
        __syncthreads();
    }
    if (t == 0) bsum[blockIdx.x] = s[0];
}

// pass 2: exclusive scan of block sums (nb <= 256), write total to row_ptr[N]
__global__ __launch_bounds__(256) void scan_bsum_kernel(int* bsum, int* row_ptr, int nb, int N) {
    __shared__ int s[256];
    int t = threadIdx.x;
    int v = (t < nb) ? bsum[t] : 0;
    s[t] = v;
    __syncthreads();
    for (int off = 1; off < 256; off <<= 1) {
        int u = (t >= off) ? s[t - off] : 0;
        __syncthreads();
        s[t] += u;
        __syncthreads();
    }
    if (t < nb) bsum[t] = s[t] - v;  // exclusive
    if (t == 255) row_ptr[N] = s[255];
}

// pass 3: block-local exclusive scan + block offset -> row_ptr, cursor
__global__ __launch_bounds__(256) void scan_write_kernel(const unsigned* deg, const int* bsum,
                                                         int* row_ptr, int* cursor, int N) {
    __shared__ int s[256];
    int t = threadIdx.x;
    int base = blockIdx.x * 1024 + t * 4;
    int d[4];
    int sum = 0;
#pragma unroll
    for (int j = 0; j < 4; j++) {
        int idx = base + j;
        d[j] = (idx < N) ? (int)deg[idx] : 0;
        sum += d[j];
    }
    s[t] = sum;
    __syncthreads();
    for (int off = 1; off < 256; off <<= 1) {
        int u = (t >= off) ? s[t - off] : 0;
        __syncthreads();
        s[t] += u;
        __syncthreads();
    }
    int run = bsum[blockIdx.x] + s[t] - sum;  // exclusive prefix at this thread's chunk
#pragma unroll
    for (int j = 0; j < 4; j++) {
        int idx = base + j;
        if (idx < N) {
            row_ptr[idx] = run;
            cursor[idx] = run;
            run += d[j];
        }
    }
}

// ---------------- scatter edges into CSR (by dst); store src and w=dinv[src] ----------------
__global__ void scatter_kernel(const int* ei32, const long long* ei64, const int* flag,
                               const float* dinv, int* cursor, int* csr_src, float* csr_w,
                               int E) {
    int e = blockIdx.x * blockDim.x + threadIdx.x;
    if (e >= E) return;
    int mode = *flag;
    int s, d;
    if (mode) {
        s = (int)ei64[e];
        d = (int)ei64[(size_t)E + e];
    } else {
        s = ei32[e];
        d = ei32[(size_t)E + e];
    }
    int pos = atomicAdd(&cursor[d], 1);
    csr_src[pos] = s;
    csr_w[pos] = dinv[s];
}

// ---------------- fp32 GEMM: out[M x DO] = A[M x 128] @ W[128 x DO] ----------------
template <int DO>
__global__ __launch_bounds__(256, 2) void gemm_kernel(const float* __restrict__ A,
                                                      const float* __restrict__ W,
                                                      float* __restrict__ out, int M) {
    constexpr int CG  = DO / 4;    // col groups of 4
    constexpr int TYN = 256 / CG;  // row groups
    constexpr int RM  = 64 / TYN;  // rows per thread
    __shared__ float As[64 * 64];
    __shared__ float Bs[64 * DO];
    const int tid = threadIdx.x;
    const int row0 = blockIdx.x * 64;
    const int tx = tid % CG, ty = tid / CG;

    float acc[RM][4];
#pragma unroll
    for (int r = 0; r < RM; r++) acc[r][0] = acc[r][1] = acc[r][2] = acc[r][3] = 0.f;

    for (int k0 = 0; k0 < 128; k0 += 64) {
        for (int idx = tid; idx < 64 * 16; idx += 256) {
            int r = idx >> 4, cc = idx & 15;
            int row = row0 + r;
            float4 v = make_float4(0.f, 0.f, 0.f, 0.f);
            if (row < M) v = ((const float4*)A)[(size_t)row * 32 + (k0 >> 2) + cc];
            ((float4*)As)[idx] = v;
        }
        for (int idx = tid; idx < 64 * CG; idx += 256) {
            int r = idx / CG, cc = idx % CG;
            ((float4*)Bs)[idx] = ((const float4*)W)[(size_t)(k0 + r) * CG + cc];
        }
        __syncthreads();
#pragma unroll 8
        for (int k = 0; k < 64; k++) {
            float4 b = ((const float4*)Bs)[k * CG + tx];
#pragma unroll
            for (int r = 0; r < RM; r++) {
                float a = As[(ty * RM + r) * 64 + k];
                acc[r][0] = fmaf(a, b.x, acc[r][0]);
                acc[r][1] = fmaf(a, b.y, acc[r][1]);
                acc[r][2] = fmaf(a, b.z, acc[r][2]);
                acc[r][3] = fmaf(a, b.w, acc[r][3]);
            }
        }
        __syncthreads();
    }
#pragma unroll
    for (int r = 0; r < RM; r++) {
        int row = row0 + ty * RM + r;
        if (row < M) {
            float4 v = make_float4(acc[r][0], acc[r][1], acc[r][2], acc[r][3]);
            ((float4*)out)[(size_t)row * CG + tx] = v;
        }
    }
}

// ---------------- CSR aggregation: out[i] = dinv[i]*(dinv[i]*h[i] + sum_e w_e*h[src_e]) + b
template <int D, bool RELU>
__global__ __launch_bounds__(128) void agg_kernel(const float* __restrict__ h,
                                                  const int* __restrict__ csr_src,
                                                  const float* __restrict__ csr_w,
                                                  const int* __restrict__ row_ptr,
                                                  const float* __restrict__ dinv,
                                                  const float* __restrict__ bias,
                                                  float* __restrict__ out, int N) {
    constexpr int CHUNK = 128;
    __shared__ int s_src[CHUNK];
    __shared__ float s_w[CHUNK];
    const int i = blockIdx.x;
    const int c = threadIdx.x;
    const float di = dinv[i];
    float acc = di * h[(size_t)i * D + c];  // self loop (outer di applied at end)
    const int start = row_ptr[i], end = row_ptr[i + 1];
    for (int base = start; base < end; base += CHUNK) {
        int m = min(CHUNK, end - base);
        for (int j = c; j < m; j += D) {
            s_src[j] = csr_src[base + j];
            s_w[j] = csr_w[base + j];
        }
        __syncthreads();
        for (int j = 0; j < m; j++) {
            acc = fmaf(s_w[j], h[(size_t)s_src[j] * D + c], acc);
        }
        __syncthreads();
    }
    float r = di * acc + bias[c];
    out[(size_t)i * D + c] = RELU ? fmaxf(r, 0.f) : r;
}

extern "C" void kernel_launch(void* const* d_in, const int* in_sizes, int n_in,
                              void* d_out, int out_size, void* d_ws, size_t ws_size,
                              hipStream_t stream) {
    const float* x  = (const float*)d_in[0];
    const void*  ei = d_in[1];
    const float* W1 = (const float*)d_in[2];
    const float* b1 = (const float*)d_in[3];
    const float* W2 = (const float*)d_in[4];
    const float* b2 = (const float*)d_in[5];
    float* out = (float*)d_out;

    const int N = in_sizes[0] / DIN;
    const int E = in_sizes[1] / 2;

    char* ws = (char*)d_ws;
    size_t off = 0;
    auto alloc = [&](size_t bytes) -> void* {
        void* p = ws + off;
        off += (bytes + 255) & ~(size_t)255;
        return p;
    };
    unsigned* deg   = (unsigned*)alloc((size_t)N * 4);
    float*    dinv  = (float*)alloc((size_t)N * 4);
    int*      rowp  = (int*)alloc((size_t)(N + 1) * 4);
    int*      curs  = (int*)alloc((size_t)N * 4);
    int*      flag  = (int*)alloc(256);
    int*      bsum  = (int*)alloc(1024 * 4);
    int*      csrs  = (int*)alloc((size_t)E * 4);
    float*    csrw  = (float*)alloc((size_t)E * 4);
    float*    h1    = (float*)alloc((size_t)N * DHID * 4);
    float*    o1    = (float*)alloc((size_t)N * DHID * 4);
    float*    h2    = h1;  // h1 dead after agg1; reuse

    const int nb = (N + 1023) / 1024;  // scan blocks (must be <= 256)

    hipMemsetAsync(deg, 0, (size_t)N * 4, stream);
    detect_i64_kernel<<<1, 64, 0, stream>>>((const unsigned*)ei, flag);
    deg_count_kernel<<<(E + 255) / 256, 256, 0, stream>>>((const int*)ei, (const long long*)ei,
                                                          flag, deg, E);
    dinv_kernel<<<(N + 255) / 256, 256, 0, stream>>>(deg, dinv, N);
    scan_blocksum_kernel<<<nb, 256, 0, stream>>>(deg, bsum, N);
    scan_bsum_kernel<<<1, 256, 0, stream>>>(bsum, rowp, nb, N);
    scan_write_kernel<<<nb, 256, 0, stream>>>(deg, bsum, rowp, curs, N);
    scatter_kernel<<<(E + 255) / 256, 256, 0, stream>>>((const int*)ei, (const long long*)ei,
                                                        flag, dinv, curs, csrs, csrw, E);
    gemm_kernel<DHID><<<(N + 63) / 64, 256, 0, stream>>>(x, W1, h1, N);
    agg_kernel<DHID, true><<<N, DHID, 0, stream>>>(h1, csrs, csrw, rowp, dinv, b1, o1, N);
    gemm_kernel<DOUT2><<<(N + 63) / 64, 256, 0, stream>>>(o1, W2, h2, N);
    agg_kernel<DOUT2, false><<<N, DOUT2, 0, stream>>>(h2, csrs, csrw, rowp, dinv, b2, out, N);
}

// Round 3
// 269.178 us; speedup vs baseline: 1.4791x; 1.0564x over previous
//
#include <hip/hip_runtime.h>
#include <hip/hip_bf16.h>
#include <stdint.h>

#define DIN 128
#define DHID 128
#define DOUT2 64

// fp32 -> bf16 (round to nearest even), as raw ushort
__device__ __forceinline__ unsigned short f2bf(float f) {
    unsigned u = __float_as_uint(f);
    u += 0x7fffu + ((u >> 16) & 1u);
    return (unsigned short)(u >> 16);
}
__device__ __forceinline__ float bf2f(unsigned short b) {
    return __uint_as_float(((unsigned)b) << 16);
}

// ---------------- dtype detector (int32 vs int64 edge_index) ----------------
__global__ void detect_i64_kernel(const unsigned* ei, int* flag) {
    int t = threadIdx.x;
    unsigned hi = ei[2 * t + 1];
    unsigned long long vote = __ballot(hi == 0u);
    if (t == 0) *flag = (vote == ~0ull) ? 1 : 0;
}

// ---------------- degree count (dst side, excluding self loops) ----------------
__global__ void deg_count_kernel(const int* ei32, const long long* ei64, const int* flag,
                                 unsigned* deg, int E) {
    int e = blockIdx.x * blockDim.x + threadIdx.x;
    if (e >= E) return;
    int mode = *flag;
    int d = mode ? (int)ei64[(size_t)E + e] : ei32[(size_t)E + e];
    atomicAdd(&deg[d], 1u);
}

// ---------------- dinv = 1/sqrt(deg+1)  (self loop adds 1) ----------------
__global__ void dinv_kernel(const unsigned* deg, float* dinv, int N) {
    int i = blockIdx.x * blockDim.x + threadIdx.x;
    if (i < N) dinv[i] = 1.0f / sqrtf((float)(deg[i] + 1u));
}

// ---------------- hierarchical exclusive scan: deg -> row_ptr, cursor ----------------
__global__ __launch_bounds__(256) void scan_blocksum_kernel(const unsigned* deg, int* bsum,
                                                            int N) {
    __shared__ int s[256];
    int t = threadIdx.x;
    int base = blockIdx.x * 1024 + t * 4;
    int sum = 0;
    if (base + 3 < N) {
        int4 v = *(const int4*)((const int*)deg + base);
        sum = v.x + v.y + v.z + v.w;
    } else {
        for (int j = 0; j < 4; j++)
            if (base + j < N) sum += (int)deg[base + j];
    }
    s[t] = sum;
    __syncthreads();
    for (int off = 128; off > 0; off >>= 1) {
        if (t < off) s[t] += s[t + off];
        __syncthreads();
    }
    if (t == 0) bsum[blockIdx.x] = s[0];
}

__global__ __launch_bounds__(256) void scan_bsum_kernel(int* bsum, int* row_ptr, int nb, int N) {
    __shared__ int s[256];
    int t = threadIdx.x;
    int v = (t < nb) ? bsum[t] : 0;
    s[t] = v;
    __syncthreads();
    for (int off = 1; off < 256; off <<= 1) {
        int u = (t >= off) ? s[t - off] : 0;
        __syncthreads();
        s[t] += u;
        __syncthreads();
    }
    if (t < nb) bsum[t] = s[t] - v;  // exclusive
    if (t == 255) row_ptr[N] = s[255];
}

__global__ __launch_bounds__(256) void scan_write_kernel(const unsigned* deg, const int* bsum,
                                                         int* row_ptr, int* cursor, int N) {
    __shared__ int s[256];
    int t = threadIdx.x;
    int base = blockIdx.x * 1024 + t * 4;
    int d[4];
    int sum = 0;
#pragma unroll
    for (int j = 0; j < 4; j++) {
        int idx = base + j;
        d[j] = (idx < N) ? (int)deg[idx] : 0;
        sum += d[j];
    }
    s[t] = sum;
    __syncthreads();
    for (int off = 1; off < 256; off <<= 1) {
        int u = (t >= off) ? s[t - off] : 0;
        __syncthreads();
        s[t] += u;
        __syncthreads();
    }
    int run = bsum[blockIdx.x] + s[t] - sum;
#pragma unroll
    for (int j = 0; j < 4; j++) {
        int idx = base + j;
        if (idx < N) {
            row_ptr[idx] = run;
            cursor[idx] = run;
            run += d[j];
        }
    }
}

// ---------------- scatter edges into CSR (by dst); store src and w=dinv[src] ----------------
__global__ void scatter_kernel(const int* ei32, const long long* ei64, const int* flag,
                               const float* dinv, int* cursor, int* csr_src, float* csr_w,
                               int E) {
    int e = blockIdx.x * blockDim.x + threadIdx.x;
    if (e >= E) return;
    int mode = *flag;
    int s, d;
    if (mode) {
        s = (int)ei64[e];
        d = (int)ei64[(size_t)E + e];
    } else {
        s = ei32[e];
        d = ei32[(size_t)E + e];
    }
    int pos = atomicAdd(&cursor[d], 1);
    csr_src[pos] = s;
    csr_w[pos] = dinv[s];
}

// ---------------- fp32 GEMM: out_bf16[M x DO] = A[M x 128] @ W[128 x DO] ----------------
template <int DO>
__global__ __launch_bounds__(256, 2) void gemm_kernel(const float* __restrict__ A,
                                                      const float* __restrict__ W,
                                                      unsigned short* __restrict__ out, int M) {
    constexpr int CG  = DO / 4;    // col groups of 4
    constexpr int TYN = 256 / CG;  // row groups
    constexpr int RM  = 64 / TYN;  // rows per thread
    __shared__ float As[64 * 64];
    __shared__ float Bs[64 * DO];
    const int tid = threadIdx.x;
    const int row0 = blockIdx.x * 64;
    const int tx = tid % CG, ty = tid / CG;

    float acc[RM][4];
#pragma unroll
    for (int r = 0; r < RM; r++) acc[r][0] = acc[r][1] = acc[r][2] = acc[r][3] = 0.f;

    for (int k0 = 0; k0 < 128; k0 += 64) {
        for (int idx = tid; idx < 64 * 16; idx += 256) {
            int r = idx >> 4, cc = idx & 15;
            int row = row0 + r;
            float4 v = make_float4(0.f, 0.f, 0.f, 0.f);
            if (row < M) v = ((const float4*)A)[(size_t)row * 32 + (k0 >> 2) + cc];
            ((float4*)As)[idx] = v;
        }
        for (int idx = tid; idx < 64 * CG; idx += 256) {
            int r = idx / CG, cc = idx % CG;
            ((float4*)Bs)[idx] = ((const float4*)W)[(size_t)(k0 + r) * CG + cc];
        }
        __syncthreads();
#pragma unroll 8
        for (int k = 0; k < 64; k++) {
            float4 b = ((const float4*)Bs)[k * CG + tx];
#pragma unroll
            for (int r = 0; r < RM; r++) {
                float a = As[(ty * RM + r) * 64 + k];
                acc[r][0] = fmaf(a, b.x, acc[r][0]);
                acc[r][1] = fmaf(a, b.y, acc[r][1]);
                acc[r][2] = fmaf(a, b.z, acc[r][2]);
                acc[r][3] = fmaf(a, b.w, acc[r][3]);
            }
        }
        __syncthreads();
    }
#pragma unroll
    for (int r = 0; r < RM; r++) {
        int row = row0 + ty * RM + r;
        if (row < M) {
            ushort4 v;
            v.x = f2bf(acc[r][0]);
            v.y = f2bf(acc[r][1]);
            v.z = f2bf(acc[r][2]);
            v.w = f2bf(acc[r][3]);
            ((ushort4*)out)[(size_t)row * CG + tx] = v;
        }
    }
}

// ---------------- CSR aggregation (bf16 gather, fp32 accumulate) ----------------
// out[i] = dinv[i]*(dinv[i]*h[i] + sum_e w_e*h[src_e]) + b
template <int D, bool RELU>
__global__ __launch_bounds__(128) void agg_kernel(const unsigned short* __restrict__ h,
                                                  const int* __restrict__ csr_src,
                                                  const float* __restrict__ csr_w,
                                                  const int* __restrict__ row_ptr,
                                                  const float* __restrict__ dinv,
                                                  const float* __restrict__ bias,
                                                  float* __restrict__ out, int N) {
    constexpr int CHUNK = 128;
    __shared__ int s_src[CHUNK];
    __shared__ float s_w[CHUNK];
    const int i = blockIdx.x;
    const int c = threadIdx.x;
    const float di = dinv[i];
    float acc = di * bf2f(h[(size_t)i * D + c]);  // self loop
    const int start = row_ptr[i], end = row_ptr[i + 1];
    for (int base = start; base < end; base += CHUNK) {
        int m = min(CHUNK, end - base);
        for (int j = c; j < m; j += D) {
            s_src[j] = csr_src[base + j];
            s_w[j] = csr_w[base + j];
        }
        __syncthreads();
        for (int j = 0; j < m; j++) {
            acc = fmaf(s_w[j], bf2f(h[(size_t)s_src[j] * D + c]), acc);
        }
        __syncthreads();
    }
    float r = di * acc + bias[c];
    out[(size_t)i * D + c] = RELU ? fmaxf(r, 0.f) : r;
}

extern "C" void kernel_launch(void* const* d_in, const int* in_sizes, int n_in,
                              void* d_out, int out_size, void* d_ws, size_t ws_size,
                              hipStream_t stream) {
    const float* x  = (const float*)d_in[0];
    const void*  ei = d_in[1];
    const float* W1 = (const float*)d_in[2];
    const float* b1 = (const float*)d_in[3];
    const float* W2 = (const float*)d_in[4];
    const float* b2 = (const float*)d_in[5];
    float* out = (float*)d_out;

    const int N = in_sizes[0] / DIN;
    const int E = in_sizes[1] / 2;

    char* ws = (char*)d_ws;
    size_t off = 0;
    auto alloc = [&](size_t bytes) -> void* {
        void* p = ws + off;
        off += (bytes + 255) & ~(size_t)255;
        return p;
    };
    unsigned*       deg  = (unsigned*)alloc((size_t)N * 4);
    float*          dinv = (float*)alloc((size_t)N * 4);
    int*            rowp = (int*)alloc((size_t)(N + 1) * 4);
    int*            curs = (int*)alloc((size_t)N * 4);
    int*            flag = (int*)alloc(256);
    int*            bsum = (int*)alloc(1024 * 4);
    int*            csrs = (int*)alloc((size_t)E * 4);
    float*          csrw = (float*)alloc((size_t)E * 4);
    unsigned short* h1   = (unsigned short*)alloc((size_t)N * DHID * 2);  // bf16
    float*          o1   = (float*)alloc((size_t)N * DHID * 4);           // fp32
    unsigned short* h2   = h1;  // h1 dead after agg1; reuse (bf16, smaller)

    const int nb = (N + 1023) / 1024;

    hipMemsetAsync(deg, 0, (size_t)N * 4, stream);
    detect_i64_kernel<<<1, 64, 0, stream>>>((const unsigned*)ei, flag);
    deg_count_kernel<<<(E + 255) / 256, 256, 0, stream>>>((const int*)ei, (const long long*)ei,
                                                          flag, deg, E);
    dinv_kernel<<<(N + 255) / 256, 256, 0, stream>>>(deg, dinv, N);
    scan_blocksum_kernel<<<nb, 256, 0, stream>>>(deg, bsum, N);
    scan_bsum_kernel<<<1, 256, 0, stream>>>(bsum, rowp, nb, N);
    scan_write_kernel<<<nb, 256, 0, stream>>>(deg, bsum, rowp, curs, N);
    scatter_kernel<<<(E + 255) / 256, 256, 0, stream>>>((const int*)ei, (const long long*)ei,
                                                        flag, dinv, curs, csrs, csrw, E);
    gemm_kernel<DHID><<<(N + 63) / 64, 256, 0, stream>>>(x, W1, h1, N);
    agg_kernel<DHID, true><<<N, DHID, 0, stream>>>(h1, csrs, csrw, rowp, dinv, b1, o1, N);
    gemm_kernel<DOUT2><<<(N + 63) / 64, 256, 0, stream>>>(o1, W2, h2, N);
    agg_kernel<DOUT2, false><<<N, DOUT2, 0, stream>>>(h2, csrs, csrw, rowp, dinv, b2, out, N);
}